// Round 7
// baseline (166.268 us; speedup 1.0000x reference)
//
#include <hip/hip_runtime.h>

#define NN 768
#define FD 256
#define HD 128

__device__ __forceinline__ float relu(float x) { return x > 0.f ? x : 0.f; }
__device__ __forceinline__ void fma4(float4& a, float s, float4 v) {
    a.x = fmaf(s, v.x, a.x); a.y = fmaf(s, v.y, a.y);
    a.z = fmaf(s, v.z, a.z); a.w = fmaf(s, v.w, a.w);
}
__device__ __forceinline__ float rdot(float4 a, float4 b, float4 w) {
    float s = relu(a.x + b.x) * w.x;
    s = fmaf(relu(a.y + b.y), w.y, s);
    s = fmaf(relu(a.z + b.z), w.z, s);
    s = fmaf(relu(a.w + b.w), w.w, s);
    return s;
}

// ---------- shared LDS layout for the two GCN kernels (54.6 KB) ----------
struct GcnLds {
    float tinL[48][132];    // one 48-row tin chunk, padded
    float adjs[3][772];     // 3 adj rows
    float part[3][12][128]; // jp partials (reused by epilogue)
    float gs[3][128];       // h (post-relu) rows
};

// Aggregation: gs[r][k] = relu(dinv[i0+r] * (sum_j adj[i0+r][j]*tin[j][k] + tin[i0+r][k]))
// 384 threads: jp = tid>>5 (0..11), kq = tid&31. Register-prefetch pipeline over 16 chunks of 48 j.
__device__ __forceinline__ void gcn_agg(GcnLds* L, const float* __restrict__ adj,
                                        const float* __restrict__ dinv,
                                        const float* __restrict__ tin, int i0, int tid) {
    // stage 3 adj rows
    for (int f = tid; f < 576; f += 384) {
        int r = f / 192, c4 = f % 192;
        *(float4*)&L->adjs[r][c4 * 4] = *(const float4*)&adj[(i0 + r) * NN + c4 * 4];
    }
    int jp = tid >> 5, kq = tid & 31;
    float4 st[4];
#pragma unroll
    for (int it = 0; it < 4; ++it) {     // preload chunk 0
        int f = it * 384 + tid; int j = f >> 5, k4 = f & 31;
        st[it] = *(const float4*)&tin[j * HD + k4 * 4];
    }
#pragma unroll
    for (int it = 0; it < 4; ++it) {     // write chunk 0 to LDS
        int f = it * 384 + tid; int j = f >> 5, k4 = f & 31;
        *(float4*)&L->tinL[j][k4 * 4] = st[it];
    }
    float4 a0 = {0,0,0,0}, a1 = {0,0,0,0}, a2 = {0,0,0,0};
    __syncthreads();
    for (int c = 0; c < 16; ++c) {
        if (c < 15) {                    // issue next-chunk loads (no wait)
            int jn = (c + 1) * 48;
#pragma unroll
            for (int it = 0; it < 4; ++it) {
                int f = it * 384 + tid; int j = f >> 5, k4 = f & 31;
                st[it] = *(const float4*)&tin[(jn + j) * HD + k4 * 4];
            }
        }
        int jb = c * 48;
#pragma unroll
        for (int jj = 0; jj < 4; ++jj) { // compute chunk c from LDS
            int j = jp * 4 + jj;
            float4 tv = *(float4*)&L->tinL[j][kq * 4];
            int ja = jb + j;
            float w0 = L->adjs[0][ja], w1 = L->adjs[1][ja], w2 = L->adjs[2][ja];
            fma4(a0, w0, tv); fma4(a1, w1, tv); fma4(a2, w2, tv);
        }
        __syncthreads();                 // all reads of tinL done
        if (c < 15) {
#pragma unroll
            for (int it = 0; it < 4; ++it) {
                int f = it * 384 + tid; int j = f >> 5, k4 = f & 31;
                *(float4*)&L->tinL[j][k4 * 4] = st[it];
            }
        }
        __syncthreads();                 // writes visible
    }
    *(float4*)&L->part[0][jp][kq * 4] = a0;
    *(float4*)&L->part[1][jp][kq * 4] = a1;
    *(float4*)&L->part[2][jp][kq * 4] = a2;
    __syncthreads();
    {   // combine partials + self loop + relu
        int r = tid >> 7, k = tid & 127;
        float s = 0.f;
#pragma unroll
        for (int u = 0; u < 12; ++u) s += L->part[r][u][k];
        s += tin[(i0 + r) * HD + k];
        L->gs[r][k] = relu(dinv[i0 + r] * s);
    }
    __syncthreads();
}

// K2: t2D[i] = dinv[i] * (h1[i] @ w2)
__global__ __launch_bounds__(384) void k_gcn_w(
        const float* __restrict__ adj, const float* __restrict__ dinv,
        const float* __restrict__ tin, const float* __restrict__ w2,
        float* __restrict__ outD) {
    __shared__ GcnLds L;
    int tid = threadIdx.x, i0 = blockIdx.x * 3;
    gcn_agg(&L, adj, dinv, tin, i0, tid);
    int r = tid >> 7, ms = (tid >> 5) & 3, kq = tid & 31;
    const float4* w24 = (const float4*)w2;
    float4 acc = {0,0,0,0};
#pragma unroll
    for (int u = 0; u < 32; ++u) {
        int m = ms * 32 + u;
        fma4(acc, L.gs[r][m], w24[m * 32 + kq]);
    }
    *(float4*)&L.part[r][ms][kq * 4] = acc;
    __syncthreads();
    int k = tid & 127;
    float s = L.part[r][0][k] + L.part[r][1][k] + L.part[r][2][k] + L.part[r][3][k];
    outD[(i0 + r) * HD + k] = dinv[i0 + r] * s;
}

// K3: p[i] = h2[i] @ we1[:H] + c ; q[i] = h2[i] @ we1[H:2H]
__global__ __launch_bounds__(384) void k_gcn_pq(
        const float* __restrict__ adj, const float* __restrict__ dinv,
        const float* __restrict__ tin, const float* __restrict__ we1,
        const float* __restrict__ cvec, float* __restrict__ p, float* __restrict__ q) {
    __shared__ GcnLds L;
    int tid = threadIdx.x, i0 = blockIdx.x * 3;
    gcn_agg(&L, adj, dinv, tin, i0, tid);
    int r = tid >> 7, ms = (tid >> 5) & 3, kq = tid & 31;
    const float4* we14 = (const float4*)we1;
    float4 ap = {0,0,0,0}, aq = {0,0,0,0};
#pragma unroll
    for (int u = 0; u < 32; ++u) {
        int m = ms * 32 + u;
        float g = L.gs[r][m];
        fma4(ap, g, we14[m * 32 + kq]);
        fma4(aq, g, we14[(HD + m) * 32 + kq]);
    }
    *(float4*)&L.part[r][ms][kq * 4] = ap;
    *(float4*)&L.part[r][ms + 4][kq * 4] = aq;
    __syncthreads();
    int k = tid & 127;
    float sp = L.part[r][0][k] + L.part[r][1][k] + L.part[r][2][k] + L.part[r][3][k];
    float sq = L.part[r][4][k] + L.part[r][5][k] + L.part[r][6][k] + L.part[r][7][k];
    p[(i0 + r) * HD + k] = cvec[k] + sp;
    q[(i0 + r) * HD + k] = sq;
}

// K1: blocks 0..255: dinv + t1D = dinv*(x@w1); block 256: cvec.
__global__ __launch_bounds__(384) void k_prep(
        const float* __restrict__ x, const float* __restrict__ adj,
        const float* __restrict__ w1, const float* __restrict__ temb,
        const float* __restrict__ we1, const float* __restrict__ be1,
        const int* __restrict__ tptr, float* __restrict__ dinv,
        float* __restrict__ cvec, float* __restrict__ t1D) {
    int b = blockIdx.x, tid = threadIdx.x;
    if (b == 256) {
        __shared__ float ts[HD];
        __shared__ float pc[2][HD];
        if (tid < HD) ts[tid] = temb[tptr[0] * HD + tid];
        __syncthreads();
        if (tid < 256) {
            int ms = tid >> 7, k = tid & 127;
            float a = 0.f;
            for (int u = 0; u < 64; ++u) {
                int m = ms * 64 + u;
                a = fmaf(ts[m], we1[(2 * HD + m) * HD + k], a);
            }
            pc[ms][k] = a;
        }
        __syncthreads();
        if (tid < HD) cvec[tid] = be1[tid] + pc[0][tid] + pc[1][tid];
        return;
    }
    int i0 = b * 3;
    __shared__ float xs[3][FD];
    __shared__ float part[3][4][128];
    __shared__ float red[6];
    __shared__ float sdi[3];
    if (tid < 192) {
        int r = tid >> 6, c4 = tid & 63;
        *(float4*)&xs[r][c4 * 4] = *(const float4*)&x[(i0 + r) * FD + c4 * 4];
    }
    {   // dinv: 128 threads per row
        int r = tid >> 7, s = tid & 127;
        const float4* arow4 = (const float4*)&adj[(i0 + r) * NN];
        float4 v = arow4[s];
        float sum = (v.x + v.y) + (v.z + v.w);
        if (s < 64) {
            float4 v2 = arow4[s + 128];
            sum += (v2.x + v2.y) + (v2.z + v2.w);
        }
#pragma unroll
        for (int off = 32; off > 0; off >>= 1) sum += __shfl_down(sum, off, 64);
        if ((tid & 63) == 0) red[r * 2 + ((tid >> 6) & 1)] = sum;
    }
    __syncthreads();
    if (tid < 3) {
        float d = rsqrtf(red[2 * tid] + red[2 * tid + 1] + 1.f);
        sdi[tid] = d; dinv[i0 + tid] = d;
    }
    __syncthreads();
    int r = tid >> 7, ms = (tid >> 5) & 3, kq = tid & 31;
    const float4* w14 = (const float4*)w1;
    float4 acc = {0,0,0,0};
#pragma unroll 8
    for (int u = 0; u < 64; ++u) {
        int m = ms * 64 + u;
        fma4(acc, xs[r][m], w14[m * 32 + kq]);
    }
    *(float4*)&part[r][ms][kq * 4] = acc;
    __syncthreads();
    int k = tid & 127;
    float s = part[r][0][k] + part[r][1][k] + part[r][2][k] + part[r][3][k];
    t1D[(i0 + r) * HD + k] = sdi[r] * s;
}

// K4: 16x16 tile pairs (bi<=bj -> 1176 blocks), 64 threads, 2x2 per thread, both dirs.
__global__ __launch_bounds__(64) void k_pair(
        const float* __restrict__ p, const float* __restrict__ q,
        const float* __restrict__ we2, const float* __restrict__ be2,
        float* __restrict__ out) {
    int t = blockIdx.x;
    int bj = (int)((sqrtf(8.f * t + 1.f) - 1.f) * 0.5f);
    while ((bj + 1) * (bj + 2) / 2 <= t) ++bj;
    while (bj * (bj + 1) / 2 > t) --bj;
    int bi = t - bj * (bj + 1) / 2;
    int i0 = bi * 16, j0 = bj * 16;
    __shared__ float spi[16][132], sqi[16][132], spj[16][132], sqj[16][132];
    __shared__ float w2s[HD];
    int tid = threadIdx.x;
    for (int idx = tid; idx < 512; idx += 64) {
        int r = idx >> 5, c4 = idx & 31;
        *(float4*)&spi[r][c4 * 4] = *(const float4*)&p[(i0 + r) * HD + c4 * 4];
        *(float4*)&sqi[r][c4 * 4] = *(const float4*)&q[(i0 + r) * HD + c4 * 4];
        *(float4*)&spj[r][c4 * 4] = *(const float4*)&p[(j0 + r) * HD + c4 * 4];
        *(float4*)&sqj[r][c4 * 4] = *(const float4*)&q[(j0 + r) * HD + c4 * 4];
    }
    w2s[tid] = we2[tid];
    w2s[tid + 64] = we2[tid + 64];
    __syncthreads();
    int tx = tid & 7, ty = tid >> 3;
    float accij[2][2] = {{0.f, 0.f}, {0.f, 0.f}};
    float accji[2][2] = {{0.f, 0.f}, {0.f, 0.f}};
#pragma unroll 4
    for (int k4 = 0; k4 < 32; ++k4) {
        float4 w = *(float4*)&w2s[k4 * 4];
        float4 Pi0 = *(float4*)&spi[2 * ty + 0][k4 * 4];
        float4 Pi1 = *(float4*)&spi[2 * ty + 1][k4 * 4];
        float4 Qi0 = *(float4*)&sqi[2 * ty + 0][k4 * 4];
        float4 Qi1 = *(float4*)&sqi[2 * ty + 1][k4 * 4];
        float4 Pj0 = *(float4*)&spj[2 * tx + 0][k4 * 4];
        float4 Pj1 = *(float4*)&spj[2 * tx + 1][k4 * 4];
        float4 Qj0 = *(float4*)&sqj[2 * tx + 0][k4 * 4];
        float4 Qj1 = *(float4*)&sqj[2 * tx + 1][k4 * 4];
        accij[0][0] += rdot(Pi0, Qj0, w); accji[0][0] += rdot(Pj0, Qi0, w);
        accij[0][1] += rdot(Pi0, Qj1, w); accji[0][1] += rdot(Pj1, Qi0, w);
        accij[1][0] += rdot(Pi1, Qj0, w); accji[1][0] += rdot(Pj0, Qi1, w);
        accij[1][1] += rdot(Pi1, Qj1, w); accji[1][1] += rdot(Pj1, Qi1, w);
    }
    float bias = be2[0];
#pragma unroll
    for (int e = 0; e < 2; ++e)
#pragma unroll
        for (int f = 0; f < 2; ++f) {
            int i = i0 + 2 * ty + e, j = j0 + 2 * tx + f;
            float lij = accij[e][f] + bias, lji = accji[e][f] + bias;
            float v = 0.5f * (1.f / (1.f + __expf(-lij)) + 1.f / (1.f + __expf(-lji)));
            out[i * NN + j] = v;
            out[j * NN + i] = v;
        }
}

extern "C" void kernel_launch(void* const* d_in, const int* in_sizes, int n_in,
                              void* d_out, int out_size, void* d_ws, size_t ws_size,
                              hipStream_t stream) {
    const float* x    = (const float*)d_in[0];
    const float* adj  = (const float*)d_in[1];
    const float* w1   = (const float*)d_in[2];
    const float* w2   = (const float*)d_in[3];
    const float* temb = (const float*)d_in[4];
    const float* we1  = (const float*)d_in[5];
    const float* be1  = (const float*)d_in[6];
    const float* we2  = (const float*)d_in[7];
    const float* be2  = (const float*)d_in[8];
    const int* tptr   = (const int*)d_in[9];
    float* out        = (float*)d_out;

    float* ws   = (float*)d_ws;
    float* dinv = ws;               // 768
    float* c    = ws + 768;         // 128
    float* A    = ws + 1024;        // 768*128  t1D, later p
    float* B    = A + NN * HD;      // 768*128  t2D
    float* C    = B + NN * HD;      // 768*128  q

    k_prep  <<<257, 384, 0, stream>>>(x, adj, w1, temb, we1, be1, tptr, dinv, c, A);
    k_gcn_w <<<256, 384, 0, stream>>>(adj, dinv, A, w2, B);
    k_gcn_pq<<<256, 384, 0, stream>>>(adj, dinv, B, we1, c, A, C);
    k_pair  <<<1176, 64, 0, stream>>>(A, C, we2, be2, out);
}

// Round 8
// 126.323 us; speedup vs baseline: 1.3162x; 1.3162x over previous
//
#include <hip/hip_runtime.h>

#define NN 768
#define FD 256
#define HD 128

__device__ __forceinline__ float relu(float x) { return x > 0.f ? x : 0.f; }
__device__ __forceinline__ void fma4(float4& a, float s, float4 v) {
    a.x = fmaf(s, v.x, a.x); a.y = fmaf(s, v.y, a.y);
    a.z = fmaf(s, v.z, a.z); a.w = fmaf(s, v.w, a.w);
}
__device__ __forceinline__ float rdot(float4 a, float4 b, float4 w) {
    float s = relu(a.x + b.x) * w.x;
    s = fmaf(relu(a.y + b.y), w.y, s);
    s = fmaf(relu(a.z + b.z), w.z, s);
    s = fmaf(relu(a.w + b.w), w.w, s);
    return s;
}

// K1 (R5 version): blocks 0..255 (768 thr): rows 3b..3b+2 -> dinv[i], t1D=dinv*(x@w1)
//     block 256: c[k] = temb[t]@we1[2H:] + be1
__global__ __launch_bounds__(768) void k_prep(
        const float* __restrict__ x, const float* __restrict__ adj,
        const float* __restrict__ w1, const float* __restrict__ temb,
        const float* __restrict__ we1, const float* __restrict__ be1,
        const int* __restrict__ tptr, float* __restrict__ dinv,
        float* __restrict__ cvec, float* __restrict__ t1D) {
    int b = blockIdx.x, tid = threadIdx.x;
    if (b == 256) {
        __shared__ float ts[HD];
        if (tid < HD) ts[tid] = temb[tptr[0] * HD + tid];
        __syncthreads();
        if (tid < HD) {
            float a0 = be1[tid], a1 = 0.f, a2 = 0.f, a3 = 0.f;
            for (int m = 0; m < HD; m += 4) {
                a0 = fmaf(ts[m + 0], we1[(2 * HD + m + 0) * HD + tid], a0);
                a1 = fmaf(ts[m + 1], we1[(2 * HD + m + 1) * HD + tid], a1);
                a2 = fmaf(ts[m + 2], we1[(2 * HD + m + 2) * HD + tid], a2);
                a3 = fmaf(ts[m + 3], we1[(2 * HD + m + 3) * HD + tid], a3);
            }
            cvec[tid] = (a0 + a1) + (a2 + a3);
        }
        return;
    }
    int i0 = b * 3;
    __shared__ float xs[3][FD];
    __shared__ float part[3][2][HD];
    __shared__ float red[12];
    __shared__ float sdi[3];
    if (tid < 192) {
        int row = tid >> 6, m4 = tid & 63;
        *(float4*)&xs[row][m4 * 4] = *(const float4*)&x[(i0 + row) * FD + m4 * 4];
    }
    {
        int r2 = tid >> 8, s = tid & 255;
        float sum = 0.f;
        if (s < 192) {
            float4 a = *(const float4*)&adj[(i0 + r2) * NN + s * 4];
            sum = (a.x + a.y) + (a.z + a.w);
        }
#pragma unroll
        for (int off = 32; off > 0; off >>= 1) sum += __shfl_down(sum, off, 64);
        if ((tid & 63) == 0) red[tid >> 6] = sum;
    }
    __syncthreads();
    if (tid < 3) {
        float t = (red[4 * tid] + red[4 * tid + 1]) + (red[4 * tid + 2] + red[4 * tid + 3]);
        float d = rsqrtf(t + 1.f);
        sdi[tid] = d; dinv[i0 + tid] = d;
    }
    __syncthreads();
    int r = tid >> 8, half = (tid >> 7) & 1, k = tid & 127;
    float a0 = 0.f, a1 = 0.f, a2 = 0.f, a3 = 0.f;
    for (int g = 128 * half; g < 128 * half + 128; g += 16) {
        float wv[16];
#pragma unroll
        for (int u = 0; u < 16; ++u) wv[u] = w1[(g + u) * HD + k];
#pragma unroll
        for (int u = 0; u < 16; ++u) {
            float xv = xs[r][g + u];
            if ((u & 3) == 0) a0 = fmaf(xv, wv[u], a0);
            else if ((u & 3) == 1) a1 = fmaf(xv, wv[u], a1);
            else if ((u & 3) == 2) a2 = fmaf(xv, wv[u], a2);
            else a3 = fmaf(xv, wv[u], a3);
        }
    }
    part[r][half][k] = (a0 + a1) + (a2 + a3);
    __syncthreads();
    if (half == 0) t1D[(i0 + r) * HD + k] = sdi[r] * (part[r][0][k] + part[r][1][k]);
}

// Split-k GEMM: P[seg][i][k] partial of sum_j adj[i,j]*tin[j,k] over j-seg of 48.
// 384 blocks = 24 i-tiles(32 rows) x 16 j-segs. 256 thr: 4 rows x 4 k per thread.
__global__ __launch_bounds__(256) void k_agg(const float* __restrict__ adj,
                                             const float* __restrict__ tin,
                                             float* __restrict__ P) {
    int it = blockIdx.x % 24, seg = blockIdx.x / 24;
    int i0 = it * 32, j0 = seg * 48;
    __shared__ float adjS[32][52];
    __shared__ float TS[48][132];
    int tid = threadIdx.x;
    for (int f = tid; f < 384; f += 256) {
        int r = f / 12, c4 = f % 12;
        *(float4*)&adjS[r][c4 * 4] = *(const float4*)&adj[(i0 + r) * NN + j0 + c4 * 4];
    }
    for (int f = tid; f < 1536; f += 256) {
        int r = f >> 5, c4 = f & 31;
        *(float4*)&TS[r][c4 * 4] = *(const float4*)&tin[(j0 + r) * HD + c4 * 4];
    }
    __syncthreads();
    int tk = tid & 31, tr = tid >> 5;  // rows tr*4..tr*4+3, cols tk*4..tk*4+3
    float4 acc0 = {0,0,0,0}, acc1 = {0,0,0,0}, acc2 = {0,0,0,0}, acc3 = {0,0,0,0};
#pragma unroll 6
    for (int j = 0; j < 48; ++j) {
        float4 tv = *(float4*)&TS[j][tk * 4];
        fma4(acc0, adjS[tr * 4 + 0][j], tv);
        fma4(acc1, adjS[tr * 4 + 1][j], tv);
        fma4(acc2, adjS[tr * 4 + 2][j], tv);
        fma4(acc3, adjS[tr * 4 + 3][j], tv);
    }
    float* base = P + (size_t)seg * (NN * HD) + (i0 + tr * 4) * HD + tk * 4;
    *(float4*)&base[0 * HD] = acc0;
    *(float4*)&base[1 * HD] = acc1;
    *(float4*)&base[2 * HD] = acc2;
    *(float4*)&base[3 * HD] = acc3;
}

// Reduce 16 partials + self + relu -> g; then outD = dinv * (g @ w2). 256 blocks x 384 thr.
__global__ __launch_bounds__(384) void k_fin_w(
        const float* __restrict__ P, const float* __restrict__ tin,
        const float* __restrict__ dinv, const float* __restrict__ w2,
        float* __restrict__ outD) {
    __shared__ float gs[3][HD];
    __shared__ float part[3][4][HD];
    int tid = threadIdx.x, i0 = blockIdx.x * 3;
    {
        int r = tid >> 7, k = tid & 127;
        int i = i0 + r;
        float s = tin[i * HD + k];
#pragma unroll
        for (int seg = 0; seg < 16; ++seg) s += P[(size_t)seg * (NN * HD) + i * HD + k];
        gs[r][k] = relu(dinv[i] * s);
    }
    __syncthreads();
    int r = tid >> 7, ms = (tid >> 5) & 3, kq = tid & 31;
    const float4* w24 = (const float4*)w2;
    float4 acc = {0,0,0,0};
#pragma unroll
    for (int u = 0; u < 32; ++u) {
        int m = ms * 32 + u;
        fma4(acc, gs[r][m], w24[m * 32 + kq]);
    }
    *(float4*)&part[r][ms][kq * 4] = acc;
    __syncthreads();
    int k = tid & 127;
    float s = part[r][0][k] + part[r][1][k] + part[r][2][k] + part[r][3][k];
    outD[(i0 + r) * HD + k] = dinv[i0 + r] * s;
}

// Reduce 16 partials + self + relu -> h2; p = h2@we1[:H]+c, q = h2@we1[H:2H].
__global__ __launch_bounds__(384) void k_fin_pq(
        const float* __restrict__ P, const float* __restrict__ tin,
        const float* __restrict__ dinv, const float* __restrict__ we1,
        const float* __restrict__ cvec, float* __restrict__ p, float* __restrict__ q) {
    __shared__ float gs[3][HD];
    __shared__ float part[3][8][HD];
    int tid = threadIdx.x, i0 = blockIdx.x * 3;
    {
        int r = tid >> 7, k = tid & 127;
        int i = i0 + r;
        float s = tin[i * HD + k];
#pragma unroll
        for (int seg = 0; seg < 16; ++seg) s += P[(size_t)seg * (NN * HD) + i * HD + k];
        gs[r][k] = relu(dinv[i] * s);
    }
    __syncthreads();
    int r = tid >> 7, ms = (tid >> 5) & 3, kq = tid & 31;
    const float4* we14 = (const float4*)we1;
    float4 ap = {0,0,0,0}, aq = {0,0,0,0};
#pragma unroll
    for (int u = 0; u < 32; ++u) {
        int m = ms * 32 + u;
        float g = gs[r][m];
        fma4(ap, g, we14[m * 32 + kq]);
        fma4(aq, g, we14[(HD + m) * 32 + kq]);
    }
    *(float4*)&part[r][ms][kq * 4] = ap;
    *(float4*)&part[r][ms + 4][kq * 4] = aq;
    __syncthreads();
    int k = tid & 127;
    float sp = part[r][0][k] + part[r][1][k] + part[r][2][k] + part[r][3][k];
    float sq = part[r][4][k] + part[r][5][k] + part[r][6][k] + part[r][7][k];
    p[(i0 + r) * HD + k] = cvec[k] + sp;
    q[(i0 + r) * HD + k] = sq;
}

// K4 (R5 version): 32x32 tile pairs (bi<=bj), 300 blocks, 256 thr, 2x2 per thread.
__global__ __launch_bounds__(256) void k_pair(
        const float* __restrict__ p, const float* __restrict__ q,
        const float* __restrict__ we2, const float* __restrict__ be2,
        float* __restrict__ out) {
    int t = blockIdx.x;
    int bj = (int)((sqrtf(8.f * t + 1.f) - 1.f) * 0.5f);
    while ((bj + 1) * (bj + 2) / 2 <= t) ++bj;
    while (bj * (bj + 1) / 2 > t) --bj;
    int bi = t - bj * (bj + 1) / 2;
    int i0 = bi * 32, j0 = bj * 32;
    __shared__ float spi[32][68], sqi[32][68], spj[32][68], sqj[32][68];
    __shared__ float w2s[HD];
    int tid = threadIdx.x;
    int tx = tid & 15, ty = tid >> 4;
    if (tid < HD) w2s[tid] = we2[tid];
    float accij[2][2] = {{0.f, 0.f}, {0.f, 0.f}};
    float accji[2][2] = {{0.f, 0.f}, {0.f, 0.f}};
    for (int h = 0; h < 2; ++h) {
        __syncthreads();
        int kb = h * 64;
        for (int idx = tid; idx < 512; idx += 256) {
            int r = idx >> 4, c4 = idx & 15;
            *(float4*)&spi[r][c4 * 4] = *(const float4*)&p[(i0 + r) * HD + kb + c4 * 4];
            *(float4*)&sqi[r][c4 * 4] = *(const float4*)&q[(i0 + r) * HD + kb + c4 * 4];
            *(float4*)&spj[r][c4 * 4] = *(const float4*)&p[(j0 + r) * HD + kb + c4 * 4];
            *(float4*)&sqj[r][c4 * 4] = *(const float4*)&q[(j0 + r) * HD + kb + c4 * 4];
        }
        __syncthreads();
#pragma unroll 8
        for (int k4 = 0; k4 < 16; ++k4) {
            float4 w = *(float4*)&w2s[kb + k4 * 4];
            float4 Pi0 = *(float4*)&spi[2 * ty + 0][k4 * 4];
            float4 Pi1 = *(float4*)&spi[2 * ty + 1][k4 * 4];
            float4 Qi0 = *(float4*)&sqi[2 * ty + 0][k4 * 4];
            float4 Qi1 = *(float4*)&sqi[2 * ty + 1][k4 * 4];
            float4 Pj0 = *(float4*)&spj[2 * tx + 0][k4 * 4];
            float4 Pj1 = *(float4*)&spj[2 * tx + 1][k4 * 4];
            float4 Qj0 = *(float4*)&sqj[2 * tx + 0][k4 * 4];
            float4 Qj1 = *(float4*)&sqj[2 * tx + 1][k4 * 4];
            accij[0][0] += rdot(Pi0, Qj0, w); accji[0][0] += rdot(Pj0, Qi0, w);
            accij[0][1] += rdot(Pi0, Qj1, w); accji[0][1] += rdot(Pj1, Qi0, w);
            accij[1][0] += rdot(Pi1, Qj0, w); accji[1][0] += rdot(Pj0, Qi1, w);
            accij[1][1] += rdot(Pi1, Qj1, w); accji[1][1] += rdot(Pj1, Qi1, w);
        }
    }
    float bias = be2[0];
#pragma unroll
    for (int e = 0; e < 2; ++e)
#pragma unroll
        for (int f = 0; f < 2; ++f) {
            int i = i0 + 2 * ty + e, j = j0 + 2 * tx + f;
            float lij = accij[e][f] + bias, lji = accji[e][f] + bias;
            float v = 0.5f * (1.f / (1.f + __expf(-lij)) + 1.f / (1.f + __expf(-lji)));
            out[i * NN + j] = v;
            out[j * NN + i] = v;
        }
}

extern "C" void kernel_launch(void* const* d_in, const int* in_sizes, int n_in,
                              void* d_out, int out_size, void* d_ws, size_t ws_size,
                              hipStream_t stream) {
    const float* x    = (const float*)d_in[0];
    const float* adj  = (const float*)d_in[1];
    const float* w1   = (const float*)d_in[2];
    const float* w2   = (const float*)d_in[3];
    const float* temb = (const float*)d_in[4];
    const float* we1  = (const float*)d_in[5];
    const float* be1  = (const float*)d_in[6];
    const float* we2  = (const float*)d_in[7];
    const float* be2  = (const float*)d_in[8];
    const int* tptr   = (const int*)d_in[9];
    float* out        = (float*)d_out;

    float* ws   = (float*)d_ws;
    float* dinv = ws;               // 768
    float* c    = ws + 768;         // 128
    float* A    = ws + 1024;        // t1D, later p
    float* B    = A + NN * HD;      // t2D
    float* C    = B + NN * HD;      // q
    float* P    = C + NN * HD;      // 16 x 768 x 128 split-k partials (6.3 MB)

    k_prep  <<<257, 768, 0, stream>>>(x, adj, w1, temb, we1, be1, tptr, dinv, c, A);
    k_agg   <<<384, 256, 0, stream>>>(adj, A, P);
    k_fin_w <<<256, 384, 0, stream>>>(P, A, dinv, w2, B);
    k_agg   <<<384, 256, 0, stream>>>(adj, B, P);
    k_fin_pq<<<256, 384, 0, stream>>>(P, B, dinv, we1, c, A, C);
    k_pair  <<<300, 256, 0, stream>>>(A, C, we2, be2, out);
}